// Round 1
// baseline (4998.095 us; speedup 1.0000x reference)
//
#include <hip/hip_runtime.h>
#include <stdint.h>

#define B_ 32
#define T_ 256
#define E_ 1024
#define H_ 1024
#define V_ 32000

typedef unsigned short u16;
typedef unsigned int   u32;
typedef unsigned long long u64;

typedef __attribute__((ext_vector_type(8))) short bf16x8;
typedef __attribute__((ext_vector_type(4))) float f32x4;

__device__ __forceinline__ float bf2f(u16 u){ u32 x = ((u32)u) << 16; return __uint_as_float(x); }
__device__ __forceinline__ u16  f2bf(float f){
  u32 x = __float_as_uint(f);
  u32 r = (x + 0x7fffu + ((x >> 16) & 1u)) >> 16;
  return (u16)r;
}
// XOR swizzle for [32][1024] bf16 tiles (2048 B rows): byte ^= ((row&7)<<4)
__device__ __forceinline__ u32 swz(u32 byte){ return byte ^ ((byte >> 7) & 0x70u); }

__device__ __forceinline__ void gload_lds16(const void* g, void* l){
  __builtin_amdgcn_global_load_lds((const __attribute__((address_space(1))) unsigned int*)g,
                                   (__attribute__((address_space(3))) unsigned int*)l, 16, 0, 0);
}

// ---------------- prep kernels ----------------
__global__ void k_prep_wc(const float* __restrict__ wih, const float* __restrict__ whh,
                          u16* __restrict__ Wc){
  int i = blockIdx.x * 256 + threadIdx.x;       // 0 .. 2097151 (4096*2048/4)
  int r = i >> 9; int k4 = (i & 511) << 2;
  const float* src = (k4 < 1024) ? (wih + (size_t)r * 1024 + k4)
                                 : (whh + (size_t)r * 1024 + (k4 - 1024));
  float4 v = *(const float4*)src;
  u64 pk = (u64)f2bf(v.x) | ((u64)f2bf(v.y) << 16) | ((u64)f2bf(v.z) << 32) | ((u64)f2bf(v.w) << 48);
  *(u64*)(Wc + (size_t)r * 2048 + k4) = pk;
}

__global__ void k_prep_ew(const float* __restrict__ src, u16* __restrict__ dst){
  size_t i = (size_t)(blockIdx.x * 256 + threadIdx.x) * 4;  // up to 32768000
  float4 v = *(const float4*)(src + i);
  u64 pk = (u64)f2bf(v.x) | ((u64)f2bf(v.y) << 16) | ((u64)f2bf(v.z) << 32) | ((u64)f2bf(v.w) << 48);
  *(u64*)(dst + i) = pk;
}

__global__ void k_prep_bsum(const float* __restrict__ bih, const float* __restrict__ bhh,
                            float* __restrict__ bsum){
  int i = blockIdx.x * 256 + threadIdx.x;       // 4096
  bsum[i] = bih[i] + bhh[i];
}

__global__ void k_gather_x(const int* __restrict__ words, const float* __restrict__ embed,
                           u16* __restrict__ X){
  int row = blockIdx.x;                         // 0..8191 = t*32 + b
  int t = row >> 5, b = row & 31;
  int wd = words[b * T_ + t];
  const float* src = embed + (size_t)wd * E_;
  u16* dst = X + (size_t)row * E_;
  int e = threadIdx.x * 4;
  float4 v = *(const float4*)(src + e);
  u64 pk = (u64)f2bf(v.x) | ((u64)f2bf(v.y) << 16) | ((u64)f2bf(v.z) << 32) | ((u64)f2bf(v.w) << 48);
  *(u64*)(dst + e) = pk;
}

// ---------------- sequential LSTM (persistent, 64 blocks x 512 thr) ----------------
__launch_bounds__(512, 1)
__global__ void k_lstm_seq(const u16* __restrict__ X, const u16* __restrict__ Wc,
                           const float* __restrict__ bsum, u16* __restrict__ Hall,
                           u32* __restrict__ flags){
  __shared__ u16 xbuf[32 * 1024];   // 64 KB, swizzled
  __shared__ u16 hbuf[32 * 1024];   // 64 KB, swizzled
  __shared__ float G[4 * 32 * 16];  // gate accumulators [g][m][n], 8 KB

  const int tid  = threadIdx.x;
  const int lane = tid & 63;
  const int w    = tid >> 6;        // 0..7
  const int g    = w & 3;           // gate (i,f,g,o)
  const int kh   = w >> 2;          // 0: x-half (w_ih), 1: h-half (w_hh)
  const int bid  = blockIdx.x;      // 0..63
  const int ncol0 = bid << 4;       // 16 h-columns per block

  // per-thread elementwise state (tid < 256 handles 2 columns each)
  const int ebb = tid >> 3;          // batch row 0..31
  const int enp = (tid & 7) << 1;    // col pair 0,2,..,14
  float bi0=0,bi1=0,bf0=0,bf1=0,bg0=0,bg1=0,bo0=0,bo1=0, c0=0.f, c1=0.f;
  if (tid < 256){
    int nc = ncol0 + enp;
    bi0 = bsum[nc];        bi1 = bsum[nc + 1];
    bf0 = bsum[1024 + nc]; bf1 = bsum[1024 + nc + 1];
    bg0 = bsum[2048 + nc]; bg1 = bsum[2048 + nc + 1];
    bo0 = bsum[3072 + nc]; bo1 = bsum[3072 + nc + 1];
  }

  // B operand pointer: Wc row = g*1024 + ncol0 + (lane&15); k-half + lane k-group
  const u16* Bp = Wc + ((size_t)(g * 1024 + ncol0 + (lane & 15))) * 2048
                     + (size_t)kh * 1024 + ((lane >> 4) * 8);
  const u32 base0 = ((u32)(lane & 15)) * 2048 + (((u32)lane >> 4) << 4);
  const u32 base1 = base0 + 16 * 2048;

  for (int t = 0; t < T_; ++t){
    // ---- poll: all 64 blocks finished step t-1 (flags >= t)
    {
      u32 v;
      do {
        v = __hip_atomic_load(&flags[lane << 5], __ATOMIC_RELAXED, __HIP_MEMORY_SCOPE_AGENT);
      } while (!__all((int)(v >= (u32)t)));
      asm volatile("" ::: "memory");
    }
    // ---- stage x_t and h_t into LDS (swizzled). 4096 16B-units each, 8 per thread.
    {
      const uint4* xsrc = (const uint4*)(X + (size_t)t * 32768);
      const u64*   hsrc = (const u64*)(Hall + (size_t)t * 32768);
      uint4 xv[8]; u64 hlo[8], hhi[8];
      #pragma unroll
      for (int i = 0; i < 8; ++i){
        int u = (i << 9) + tid;
        xv[i]  = xsrc[u];
        hlo[i] = __hip_atomic_load(hsrc + (size_t)u * 2,     __ATOMIC_RELAXED, __HIP_MEMORY_SCOPE_AGENT);
        hhi[i] = __hip_atomic_load(hsrc + (size_t)u * 2 + 1, __ATOMIC_RELAXED, __HIP_MEMORY_SCOPE_AGENT);
      }
      #pragma unroll
      for (int i = 0; i < 8; ++i){
        int u = (i << 9) + tid;
        u32 byte = swz((u32)u << 4);
        *(uint4*)((char*)xbuf + byte) = xv[i];
        uint4 hv; hv.x = (u32)hlo[i]; hv.y = (u32)(hlo[i] >> 32); hv.z = (u32)hhi[i]; hv.w = (u32)(hhi[i] >> 32);
        *(uint4*)((char*)hbuf + byte) = hv;
      }
    }
    __syncthreads();

    // ---- MFMA: this wave computes gate g, k-half kh, M=32 (2 tiles) x N=16
    f32x4 z = {0.f,0.f,0.f,0.f};
    f32x4 acc0 = z, acc1 = z;
    const char* abuf = kh ? (const char*)hbuf : (const char*)xbuf;
    #pragma unroll 4
    for (int kk = 0; kk < 32; ++kk){
      bf16x8 bfr = *(const bf16x8*)(Bp + kk * 32);
      bf16x8 a0  = *(const bf16x8*)(abuf + swz(base0 + (u32)kk * 64));
      bf16x8 a1  = *(const bf16x8*)(abuf + swz(base1 + (u32)kk * 64));
      acc0 = __builtin_amdgcn_mfma_f32_16x16x32_bf16(a0, bfr, acc0, 0, 0, 0);
      acc1 = __builtin_amdgcn_mfma_f32_16x16x32_bf16(a1, bfr, acc1, 0, 0, 0);
    }
    // ---- combine k-halves through LDS
    if (kh == 1){
      #pragma unroll
      for (int r2 = 0; r2 < 4; ++r2){
        int m0 = ((lane >> 4) << 2) + r2;
        G[g * 512 + m0 * 16        + (lane & 15)] = acc0[r2];
        G[g * 512 + (16 + m0) * 16 + (lane & 15)] = acc1[r2];
      }
    }
    __syncthreads();
    if (kh == 0){
      #pragma unroll
      for (int r2 = 0; r2 < 4; ++r2){
        int m0 = ((lane >> 4) << 2) + r2;
        G[g * 512 + m0 * 16        + (lane & 15)] += acc0[r2];
        G[g * 512 + (16 + m0) * 16 + (lane & 15)] += acc1[r2];
      }
    }
    __syncthreads();

    // ---- LSTM elementwise (256 threads, 2 cols each), write h_t to Hall slot t+1 via sc1
    if (tid < 256){
      int idx0 = ebb * 16 + enp;
      float gi0 = G[idx0] + bi0,          gi1 = G[idx0 + 1] + bi1;
      float gf0 = G[512 + idx0] + bf0,    gf1 = G[512 + idx0 + 1] + bf1;
      float gg0 = G[1024 + idx0] + bg0,   gg1 = G[1024 + idx0 + 1] + bg1;
      float go0 = G[1536 + idx0] + bo0,   go1 = G[1536 + idx0 + 1] + bo1;
      float i0 = 1.f / (1.f + __expf(-gi0)), i1 = 1.f / (1.f + __expf(-gi1));
      float f0 = 1.f / (1.f + __expf(-gf0)), f1 = 1.f / (1.f + __expf(-gf1));
      float q0 = tanhf(gg0), q1 = tanhf(gg1);
      float o0 = 1.f / (1.f + __expf(-go0)), o1 = 1.f / (1.f + __expf(-go1));
      c0 = f0 * c0 + i0 * q0; c1 = f1 * c1 + i1 * q1;
      float h0 = o0 * tanhf(c0), h1 = o1 * tanhf(c1);
      u32 pk = (u32)f2bf(h0) | ((u32)f2bf(h1) << 16);
      u32* dst = (u32*)(Hall + (size_t)(t + 1) * 32768 + (size_t)ebb * 1024 + ncol0 + enp);
      __hip_atomic_store(dst, pk, __ATOMIC_RELAXED, __HIP_MEMORY_SCOPE_AGENT);
    }
    __syncthreads();   // drains each wave's vmcnt -> h stores globally visible (sc1)
    if (tid == 0){
      __hip_atomic_store(&flags[bid << 5], (u32)(t + 1), __ATOMIC_RELEASE, __HIP_MEMORY_SCOPE_AGENT);
    }
  }
}

// ---------------- batched emit GEMM with fused exp-row-sum ----------------
__launch_bounds__(256)
__global__ void k_emit(const u16* __restrict__ Hall, const u16* __restrict__ Ew,
                       const float* __restrict__ emit_b, float* __restrict__ partials){
  __shared__ u16 As[128 * 32];
  __shared__ u16 Bs[128 * 32];
  __shared__ float rs[2 * 128];
  const int tid = threadIdx.x, lane = tid & 63, w = tid >> 6;
  const int wr = w >> 1, wc = w & 1;
  const int vc = blockIdx.x;   // 0..249
  const int mt = blockIdx.y;   // 0..63
  const u16* Ab = Hall + 32 * 1024 + (size_t)mt * 128 * 1024;
  const u16* Bb = Ew + (size_t)vc * 128 * 1024;

  f32x4 z = {0.f,0.f,0.f,0.f};
  f32x4 acc[4][4];
  #pragma unroll
  for (int mi = 0; mi < 4; ++mi)
    #pragma unroll
    for (int ni = 0; ni < 4; ++ni) acc[mi][ni] = z;

  for (int kk = 0; kk < 32; ++kk){
    #pragma unroll
    for (int p = 0; p < 2; ++p){
      int u = (p << 8) + tid;             // 0..511
      int row = u >> 2, seg = u & 3;
      size_t go = (size_t)row * 1024 + (size_t)kk * 32 + seg * 8;
      gload_lds16(Ab + go, (char*)As + (size_t)u * 16);
      gload_lds16(Bb + go, (char*)Bs + (size_t)u * 16);
    }
    __syncthreads();
    bf16x8 af[4], bf[4];
    #pragma unroll
    for (int mi = 0; mi < 4; ++mi){
      int row = wr * 64 + mi * 16 + (lane & 15);
      af[mi] = *(const bf16x8*)(As + row * 32 + ((lane >> 4) * 8));
    }
    #pragma unroll
    for (int ni = 0; ni < 4; ++ni){
      int row = wc * 64 + ni * 16 + (lane & 15);
      bf[ni] = *(const bf16x8*)(Bs + row * 32 + ((lane >> 4) * 8));
    }
    #pragma unroll
    for (int mi = 0; mi < 4; ++mi)
      #pragma unroll
      for (int ni = 0; ni < 4; ++ni)
        acc[mi][ni] = __builtin_amdgcn_mfma_f32_16x16x32_bf16(af[mi], bf[ni], acc[mi][ni], 0, 0, 0);
    __syncthreads();
  }

  // epilogue: exp + row-sum over this block's 128 v-columns
  float eb[4];
  #pragma unroll
  for (int ni = 0; ni < 4; ++ni)
    eb[ni] = emit_b[vc * 128 + wc * 64 + ni * 16 + (lane & 15)];
  #pragma unroll
  for (int mi = 0; mi < 4; ++mi){
    #pragma unroll
    for (int r = 0; r < 4; ++r){
      float s = 0.f;
      #pragma unroll
      for (int ni = 0; ni < 4; ++ni) s += __expf(acc[mi][ni][r] + eb[ni]);
      s += __shfl_xor(s, 1); s += __shfl_xor(s, 2); s += __shfl_xor(s, 4); s += __shfl_xor(s, 8);
      if ((lane & 15) == 0)
        rs[wc * 128 + wr * 64 + mi * 16 + ((lane >> 4) << 2) + r] = s;
    }
  }
  __syncthreads();
  if (tid < 128){
    partials[(size_t)vc * 8192 + (size_t)mt * 128 + tid] = rs[tid] + rs[128 + tid];
  }
}

// ---------------- target logit per row ----------------
__global__ void k_target(const u16* __restrict__ Hall, const u16* __restrict__ Ew,
                         const int* __restrict__ words, const float* __restrict__ emit_b,
                         float* __restrict__ tgt){
  int row  = blockIdx.x * 4 + (threadIdx.x >> 6);  // 0..8191
  int lane = threadIdx.x & 63;
  int t = row >> 5, b = row & 31;
  int wd = words[b * T_ + t];
  const bf16x8* ha = (const bf16x8*)(Hall + (size_t)(row + 32) * 1024 + lane * 16);
  const bf16x8* wa = (const bf16x8*)(Ew + (size_t)wd * 1024 + lane * 16);
  float s = 0.f;
  #pragma unroll
  for (int p = 0; p < 2; ++p){
    bf16x8 av = ha[p], wv = wa[p];
    #pragma unroll
    for (int i = 0; i < 8; ++i) s += bf2f((u16)av[i]) * bf2f((u16)wv[i]);
  }
  s += __shfl_xor(s, 32); s += __shfl_xor(s, 16); s += __shfl_xor(s, 8);
  s += __shfl_xor(s, 4);  s += __shfl_xor(s, 2);  s += __shfl_xor(s, 1);
  if (lane == 0) tgt[row] = s + emit_b[wd];
}

// ---------------- finalize: ll = tgt - log(sum exp) ----------------
__global__ void k_final(const float* __restrict__ partials, const float* __restrict__ tgt,
                        float* __restrict__ out){
  int i = blockIdx.x * 256 + threadIdx.x;    // 0..8191
  float s = 0.f;
  for (int vcb = 0; vcb < 250; ++vcb) s += partials[(size_t)vcb * 8192 + i];
  out[i] = tgt[i] - logf(s);
}

extern "C" void kernel_launch(void* const* d_in, const int* in_sizes, int n_in,
                              void* d_out, int out_size, void* d_ws, size_t ws_size,
                              hipStream_t stream){
  const int*   words = (const int*)d_in[0];
  const float* embed = (const float*)d_in[1];
  const float* wih   = (const float*)d_in[2];
  const float* whh   = (const float*)d_in[3];
  const float* bih   = (const float*)d_in[4];
  const float* bhh   = (const float*)d_in[5];
  const float* emw   = (const float*)d_in[6];
  const float* emb_b = (const float*)d_in[7];
  float* out = (float*)d_out;

  // workspace layout
  char* ws = (char*)d_ws;
  u16* Wc   = (u16*)ws;                       // 4096*2048
  u16* Ew   = Wc + 8388608ULL;                // 32000*1024
  u16* X    = Ew + 32768000ULL;               // 256*32*1024
  u16* Hall = X + 8388608ULL;                 // 257*32*1024 (slot 0 = h_init zeros)
  float* fb   = (float*)(Hall + 8421376ULL);
  float* bsum = fb;                           // 4096
  float* tgt  = fb + 4096;                    // 8192
  float* parts= fb + 4096 + 8192;             // 250*8192
  u32* flags  = (u32*)(parts + 2048000ULL);   // 64*32

  size_t need = (8388608ULL + 32768000ULL + 8388608ULL + 8421376ULL) * 2
              + (4096ULL + 8192ULL + 2048000ULL) * 4 + 64ULL * 32 * 4;
  if (ws_size < need) return;  // fail loudly via validation

  hipMemsetAsync(flags, 0, 64 * 32 * 4, stream);
  hipMemsetAsync(Hall, 0, 32 * 1024 * 2, stream);   // h_{-1} = 0

  k_prep_wc  <<<8192,  256, 0, stream>>>(wih, whh, Wc);
  k_prep_ew  <<<32000, 256, 0, stream>>>(emw, Ew);
  k_prep_bsum<<<16,    256, 0, stream>>>(bih, bhh, bsum);
  k_gather_x <<<8192,  256, 0, stream>>>(words, embed, X);
  k_lstm_seq <<<64,    512, 0, stream>>>(X, Wc, bsum, Hall, flags);
  k_emit     <<<dim3(250, 64), 256, 0, stream>>>(Hall, Ew, emb_b, parts);
  k_target   <<<2048,  256, 0, stream>>>(Hall, Ew, words, emb_b, tgt);
  k_final    <<<32,    256, 0, stream>>>(parts, tgt, out);
}

// Round 2
// 2555.655 us; speedup vs baseline: 1.9557x; 1.9557x over previous
//
#include <hip/hip_runtime.h>
#include <stdint.h>

#define B_ 32
#define T_ 256
#define E_ 1024
#define H_ 1024
#define V_ 32000

typedef unsigned short u16;
typedef unsigned int   u32;
typedef unsigned long long u64;

typedef __attribute__((ext_vector_type(8))) short bf16x8;
typedef __attribute__((ext_vector_type(4))) float f32x4;

__device__ __forceinline__ float bf2f(u16 u){ u32 x = ((u32)u) << 16; return __uint_as_float(x); }
__device__ __forceinline__ u16  f2bf(float f){
  u32 x = __float_as_uint(f);
  u32 r = (x + 0x7fffu + ((x >> 16) & 1u)) >> 16;
  return (u16)r;
}
// XOR swizzle for [32][1024] bf16 tiles (2048 B rows): byte ^= ((row&7)<<4)
__device__ __forceinline__ u32 swz(u32 byte){ return byte ^ ((byte >> 7) & 0x70u); }

__device__ __forceinline__ void gload_lds16(const void* g, void* l){
  __builtin_amdgcn_global_load_lds((const __attribute__((address_space(1))) unsigned int*)g,
                                   (__attribute__((address_space(3))) unsigned int*)l, 16, 0, 0);
}

// ---------------- prep kernels ----------------
__global__ void k_prep_wc(const float* __restrict__ wih, const float* __restrict__ whh,
                          u16* __restrict__ Wc){
  int i = blockIdx.x * 256 + threadIdx.x;       // 0 .. 2097151 (4096*2048/4)
  int r = i >> 9; int k4 = (i & 511) << 2;
  const float* src = (k4 < 1024) ? (wih + (size_t)r * 1024 + k4)
                                 : (whh + (size_t)r * 1024 + (k4 - 1024));
  float4 v = *(const float4*)src;
  u64 pk = (u64)f2bf(v.x) | ((u64)f2bf(v.y) << 16) | ((u64)f2bf(v.z) << 32) | ((u64)f2bf(v.w) << 48);
  *(u64*)(Wc + (size_t)r * 2048 + k4) = pk;
}

__global__ void k_prep_ew(const float* __restrict__ src, u16* __restrict__ dst){
  size_t i = (size_t)(blockIdx.x * 256 + threadIdx.x) * 4;  // up to 32768000
  float4 v = *(const float4*)(src + i);
  u64 pk = (u64)f2bf(v.x) | ((u64)f2bf(v.y) << 16) | ((u64)f2bf(v.z) << 32) | ((u64)f2bf(v.w) << 48);
  *(u64*)(dst + i) = pk;
}

__global__ void k_prep_bsum(const float* __restrict__ bih, const float* __restrict__ bhh,
                            float* __restrict__ bsum){
  int i = blockIdx.x * 256 + threadIdx.x;       // 4096
  bsum[i] = bih[i] + bhh[i];
}

__global__ void k_gather_x(const int* __restrict__ words, const float* __restrict__ embed,
                           u16* __restrict__ X){
  int row = blockIdx.x;                         // 0..8191 = t*32 + b
  int t = row >> 5, b = row & 31;
  int wd = words[b * T_ + t];
  const float* src = embed + (size_t)wd * E_;
  u16* dst = X + (size_t)row * E_;
  int e = threadIdx.x * 4;
  float4 v = *(const float4*)(src + e);
  u64 pk = (u64)f2bf(v.x) | ((u64)f2bf(v.y) << 16) | ((u64)f2bf(v.z) << 32) | ((u64)f2bf(v.w) << 48);
  *(u64*)(dst + e) = pk;
}

// ---------------- sequential LSTM (persistent, 64 blocks x 512 thr) ----------------
// Weights live in VGPRs (breg[32], 128 VGPR/lane). h exchanged via plain sc0/sc1
// loads/stores (HBM, cache-bypassing, NON-atomic). One global step counter.
__launch_bounds__(512, 2)
__global__ void k_lstm_seq(const u16* __restrict__ X, const u16* __restrict__ Wc,
                           const float* __restrict__ bsum, u16* __restrict__ Hall,
                           u32* __restrict__ cnt){
  __shared__ u16 xbuf[32 * 1024];   // 64 KB, swizzled
  __shared__ u16 hbuf[32 * 1024];   // 64 KB, swizzled
  __shared__ float G[4 * 32 * 16];  // gate accumulators [g][m][n], 8 KB

  const int tid  = threadIdx.x;
  const int lane = tid & 63;
  const int w    = tid >> 6;        // 0..7
  const int g    = w & 3;           // gate (i,f,g,o)
  const int kh   = w >> 2;          // 0: x-half (w_ih), 1: h-half (w_hh)
  const int bid  = blockIdx.x;      // 0..63
  const int nc0  = bid << 4;        // 16 h-columns per block

  // per-thread elementwise state (tid < 256 handles 2 columns each)
  const int ebb = tid >> 3;          // batch row 0..31
  const int enp = (tid & 7) << 1;    // col pair 0,2,..,14
  float bi0=0,bi1=0,bf0=0,bf1=0,bg0=0,bg1=0,bo0=0,bo1=0, c0=0.f, c1=0.f;
  if (tid < 256){
    int nc = nc0 + enp;
    bi0 = bsum[nc];        bi1 = bsum[nc + 1];
    bf0 = bsum[1024 + nc]; bf1 = bsum[1024 + nc + 1];
    bg0 = bsum[2048 + nc]; bg1 = bsum[2048 + nc + 1];
    bo0 = bsum[3072 + nc]; bo1 = bsum[3072 + nc + 1];
  }

  // ---- preload this wave's weight slice into VGPRs (once) ----
  // wave w: gate g, k-half kh, cols nc0..nc0+15. B-frag: col = lane&15,
  // k = kh*1024 + kk*32 + (lane>>4)*8 .. +8
  bf16x8 breg[32];
  {
    const u16* Bp = Wc + (size_t)(g * 1024 + nc0 + (lane & 15)) * 2048
                       + (size_t)kh * 1024 + ((lane >> 4) * 8);
    #pragma unroll
    for (int kk = 0; kk < 32; ++kk) breg[kk] = *(const bf16x8*)(Bp + kk * 32);
  }

  const u32 base0 = ((u32)(lane & 15)) * 2048 + (((u32)lane >> 4) << 4);
  const u32 base1 = base0 + 16 * 2048;

  for (int t = 0; t < T_; ++t){
    // ---- prefetch x_t into xbuf (linear LDS dest, inverse-swizzled source) ----
    {
      const char* Xt = (const char*)(X + (size_t)t * 32768);
      #pragma unroll
      for (int i = 0; i < 8; ++i){
        u32 d = ((u32)(i * 512 + tid)) << 4;
        gload_lds16(Xt + swz(d), (char*)xbuf + d);
      }
    }
    // ---- poll: all 64 blocks finished step t-1 (cnt >= 64*t). wave0 only. ----
    if (w == 0){
      u32 tgtv = (u32)(64 * t);
      u32 v;
      do {
        asm volatile("global_load_dword %0, %1, off sc0 sc1\n\ts_waitcnt vmcnt(0)"
                     : "=v"(v) : "v"(cnt) : "memory");
      } while (v < tgtv);   // all lanes load same address -> uniform
    }
    __syncthreads();        // x in LDS; h_t published by all blocks

    // ---- stage h_t into hbuf: plain sc0/sc1 loads (non-atomic), swizzled ds_write ----
    {
      const char* Ht = (const char*)Hall + (size_t)t * 65536;
      uint4 hv[8];
      #pragma unroll
      for (int i = 0; i < 8; ++i){
        u32 d = ((u32)(i * 512 + tid)) << 4;
        asm volatile("global_load_dwordx4 %0, %1, off sc0 sc1"
                     : "=v"(hv[i]) : "v"(Ht + d));
      }
      asm volatile("s_waitcnt vmcnt(0)" ::: "memory");
      #pragma unroll
      for (int i = 0; i < 8; ++i){
        u32 d = ((u32)(i * 512 + tid)) << 4;
        *(uint4*)((char*)hbuf + swz(d)) = hv[i];
      }
    }
    __syncthreads();

    // ---- MFMA: wave computes gate g, k-half kh, M=32 (2 tiles) x N=16, K=1024 ----
    f32x4 z = {0.f,0.f,0.f,0.f};
    f32x4 acc0 = z, acc1 = z;
    {
      const char* abuf = kh ? (const char*)hbuf : (const char*)xbuf;
      #pragma unroll
      for (int kk = 0; kk < 32; ++kk){
        bf16x8 a0 = *(const bf16x8*)(abuf + swz(base0 + (u32)kk * 64));
        bf16x8 a1 = *(const bf16x8*)(abuf + swz(base1 + (u32)kk * 64));
        acc0 = __builtin_amdgcn_mfma_f32_16x16x32_bf16(a0, breg[kk], acc0, 0, 0, 0);
        acc1 = __builtin_amdgcn_mfma_f32_16x16x32_bf16(a1, breg[kk], acc1, 0, 0, 0);
      }
    }
    // ---- combine k-halves through LDS ----
    if (kh == 1){
      #pragma unroll
      for (int r2 = 0; r2 < 4; ++r2){
        int m0 = ((lane >> 4) << 2) + r2;
        G[g * 512 + m0 * 16        + (lane & 15)] = acc0[r2];
        G[g * 512 + (16 + m0) * 16 + (lane & 15)] = acc1[r2];
      }
    }
    __syncthreads();
    if (kh == 0){
      #pragma unroll
      for (int r2 = 0; r2 < 4; ++r2){
        int m0 = ((lane >> 4) << 2) + r2;
        G[g * 512 + m0 * 16        + (lane & 15)] += acc0[r2];
        G[g * 512 + (16 + m0) * 16 + (lane & 15)] += acc1[r2];
      }
    }
    __syncthreads();

    // ---- LSTM elementwise (256 threads, 2 cols each); publish h_{t+1} ----
    if (tid < 256){
      int idx0 = ebb * 16 + enp;
      float gi0 = G[idx0] + bi0,          gi1 = G[idx0 + 1] + bi1;
      float gf0 = G[512 + idx0] + bf0,    gf1 = G[512 + idx0 + 1] + bf1;
      float gg0 = G[1024 + idx0] + bg0,   gg1 = G[1024 + idx0 + 1] + bg1;
      float go0 = G[1536 + idx0] + bo0,   go1 = G[1536 + idx0 + 1] + bo1;
      float i0 = 1.f / (1.f + __expf(-gi0)), i1 = 1.f / (1.f + __expf(-gi1));
      float f0 = 1.f / (1.f + __expf(-gf0)), f1 = 1.f / (1.f + __expf(-gf1));
      float q0 = tanhf(gg0), q1 = tanhf(gg1);
      float o0 = 1.f / (1.f + __expf(-go0)), o1 = 1.f / (1.f + __expf(-go1));
      c0 = f0 * c0 + i0 * q0; c1 = f1 * c1 + i1 * q1;
      float h0 = o0 * tanhf(c0), h1 = o1 * tanhf(c1);
      u32 pk = (u32)f2bf(h0) | ((u32)f2bf(h1) << 16);
      u32* dst = (u32*)(Hall + (size_t)(t + 1) * 32768 + (size_t)ebb * 1024 + nc0 + enp);
      asm volatile("global_store_dword %0, %1, off sc0 sc1" :: "v"(dst), "v"(pk) : "memory");
    }
    asm volatile("s_waitcnt vmcnt(0)" ::: "memory");  // ensure asm stores drained pre-barrier
    __syncthreads();
    if (tid == 0){
      __hip_atomic_fetch_add(cnt, 1u, __ATOMIC_RELEASE, __HIP_MEMORY_SCOPE_AGENT);
    }
  }
}

// ---------------- batched emit GEMM with fused exp-row-sum ----------------
__launch_bounds__(256)
__global__ void k_emit(const u16* __restrict__ Hall, const u16* __restrict__ Ew,
                       const float* __restrict__ emit_b, float* __restrict__ partials){
  __shared__ u16 As[128 * 32];
  __shared__ u16 Bs[128 * 32];
  __shared__ float rs[2 * 128];
  const int tid = threadIdx.x, lane = tid & 63, w = tid >> 6;
  const int wr = w >> 1, wc = w & 1;
  const int vc = blockIdx.x;   // 0..249
  const int mt = blockIdx.y;   // 0..63
  const u16* Ab = Hall + 32 * 1024 + (size_t)mt * 128 * 1024;
  const u16* Bb = Ew + (size_t)vc * 128 * 1024;

  f32x4 z = {0.f,0.f,0.f,0.f};
  f32x4 acc[4][4];
  #pragma unroll
  for (int mi = 0; mi < 4; ++mi)
    #pragma unroll
    for (int ni = 0; ni < 4; ++ni) acc[mi][ni] = z;

  for (int kk = 0; kk < 32; ++kk){
    #pragma unroll
    for (int p = 0; p < 2; ++p){
      int u = (p << 8) + tid;             // 0..511
      int row = u >> 2, seg = u & 3;
      size_t go = (size_t)row * 1024 + (size_t)kk * 32 + seg * 8;
      gload_lds16(Ab + go, (char*)As + (size_t)u * 16);
      gload_lds16(Bb + go, (char*)Bs + (size_t)u * 16);
    }
    __syncthreads();
    bf16x8 af[4], bf[4];
    #pragma unroll
    for (int mi = 0; mi < 4; ++mi){
      int row = wr * 64 + mi * 16 + (lane & 15);
      af[mi] = *(const bf16x8*)(As + row * 32 + ((lane >> 4) * 8));
    }
    #pragma unroll
    for (int ni = 0; ni < 4; ++ni){
      int row = wc * 64 + ni * 16 + (lane & 15);
      bf[ni] = *(const bf16x8*)(Bs + row * 32 + ((lane >> 4) * 8));
    }
    #pragma unroll
    for (int mi = 0; mi < 4; ++mi)
      #pragma unroll
      for (int ni = 0; ni < 4; ++ni)
        acc[mi][ni] = __builtin_amdgcn_mfma_f32_16x16x32_bf16(af[mi], bf[ni], acc[mi][ni], 0, 0, 0);
    __syncthreads();
  }

  // epilogue: exp + row-sum over this block's 128 v-columns
  float eb[4];
  #pragma unroll
  for (int ni = 0; ni < 4; ++ni)
    eb[ni] = emit_b[vc * 128 + wc * 64 + ni * 16 + (lane & 15)];
  #pragma unroll
  for (int mi = 0; mi < 4; ++mi){
    #pragma unroll
    for (int r = 0; r < 4; ++r){
      float s = 0.f;
      #pragma unroll
      for (int ni = 0; ni < 4; ++ni) s += __expf(acc[mi][ni][r] + eb[ni]);
      s += __shfl_xor(s, 1); s += __shfl_xor(s, 2); s += __shfl_xor(s, 4); s += __shfl_xor(s, 8);
      if ((lane & 15) == 0)
        rs[wc * 128 + wr * 64 + mi * 16 + ((lane >> 4) << 2) + r] = s;
    }
  }
  __syncthreads();
  if (tid < 128){
    partials[(size_t)vc * 8192 + (size_t)mt * 128 + tid] = rs[tid] + rs[128 + tid];
  }
}

// ---------------- target logit per row ----------------
__global__ void k_target(const u16* __restrict__ Hall, const u16* __restrict__ Ew,
                         const int* __restrict__ words, const float* __restrict__ emit_b,
                         float* __restrict__ tgt){
  int row  = blockIdx.x * 4 + (threadIdx.x >> 6);  // 0..8191
  int lane = threadIdx.x & 63;
  int t = row >> 5, b = row & 31;
  int wd = words[b * T_ + t];
  const bf16x8* ha = (const bf16x8*)(Hall + (size_t)(row + 32) * 1024 + lane * 16);
  const bf16x8* wa = (const bf16x8*)(Ew + (size_t)wd * 1024 + lane * 16);
  float s = 0.f;
  #pragma unroll
  for (int p = 0; p < 2; ++p){
    bf16x8 av = ha[p], wv = wa[p];
    #pragma unroll
    for (int i = 0; i < 8; ++i) s += bf2f((u16)av[i]) * bf2f((u16)wv[i]);
  }
  s += __shfl_xor(s, 32); s += __shfl_xor(s, 16); s += __shfl_xor(s, 8);
  s += __shfl_xor(s, 4);  s += __shfl_xor(s, 2);  s += __shfl_xor(s, 1);
  if (lane == 0) tgt[row] = s + emit_b[wd];
}

// ---------------- finalize: ll = tgt - log(sum exp) ----------------
__global__ void k_final(const float* __restrict__ partials, const float* __restrict__ tgt,
                        float* __restrict__ out){
  int i = blockIdx.x * 256 + threadIdx.x;    // 0..8191
  float s = 0.f;
  for (int vcb = 0; vcb < 250; ++vcb) s += partials[(size_t)vcb * 8192 + i];
  out[i] = tgt[i] - logf(s);
}

extern "C" void kernel_launch(void* const* d_in, const int* in_sizes, int n_in,
                              void* d_out, int out_size, void* d_ws, size_t ws_size,
                              hipStream_t stream){
  const int*   words = (const int*)d_in[0];
  const float* embed = (const float*)d_in[1];
  const float* wih   = (const float*)d_in[2];
  const float* whh   = (const float*)d_in[3];
  const float* bih   = (const float*)d_in[4];
  const float* bhh   = (const float*)d_in[5];
  const float* emw   = (const float*)d_in[6];
  const float* emb_b = (const float*)d_in[7];
  float* out = (float*)d_out;

  // workspace layout
  char* ws = (char*)d_ws;
  u16* Wc   = (u16*)ws;                       // 4096*2048
  u16* Ew   = Wc + 8388608ULL;                // 32000*1024
  u16* X    = Ew + 32768000ULL;               // 256*32*1024
  u16* Hall = X + 8388608ULL;                 // 257*32*1024 (slot 0 = h_init zeros)
  float* fb   = (float*)(Hall + 8421376ULL);
  float* bsum = fb;                           // 4096
  float* tgt  = fb + 4096;                    // 8192
  float* parts= fb + 4096 + 8192;             // 250*8192
  u32* cnt    = (u32*)(parts + 2048000ULL);   // step counter (+ padding)

  size_t need = (8388608ULL + 32768000ULL + 8388608ULL + 8421376ULL) * 2
              + (4096ULL + 8192ULL + 2048000ULL) * 4 + 64ULL * 32 * 4;
  if (ws_size < need) return;  // fail loudly via validation

  hipMemsetAsync(cnt, 0, 64 * 32 * 4, stream);
  hipMemsetAsync(Hall, 0, 32 * 1024 * 2, stream);   // h_{-1} = 0

  k_prep_wc  <<<8192,  256, 0, stream>>>(wih, whh, Wc);
  k_prep_ew  <<<32000, 256, 0, stream>>>(emw, Ew);
  k_prep_bsum<<<16,    256, 0, stream>>>(bih, bhh, bsum);
  k_gather_x <<<8192,  256, 0, stream>>>(words, embed, X);
  k_lstm_seq <<<64,    512, 0, stream>>>(X, Wc, bsum, Hall, cnt);
  k_emit     <<<dim3(250, 64), 256, 0, stream>>>(Hall, Ew, emb_b, parts);
  k_target   <<<2048,  256, 0, stream>>>(Hall, Ew, words, emb_b, tgt);
  k_final    <<<32,    256, 0, stream>>>(parts, tgt, out);
}

// Round 3
// 2326.861 us; speedup vs baseline: 2.1480x; 1.0983x over previous
//
#include <hip/hip_runtime.h>
#include <stdint.h>

#define B_ 32
#define T_ 256
#define E_ 1024
#define H_ 1024
#define V_ 32000

typedef unsigned short u16;
typedef unsigned int   u32;
typedef unsigned long long u64;

typedef __attribute__((ext_vector_type(8))) short bf16x8;
typedef __attribute__((ext_vector_type(4))) float f32x4;

__device__ __forceinline__ float bf2f(u16 u){ u32 x = ((u32)u) << 16; return __uint_as_float(x); }
__device__ __forceinline__ u16  f2bf(float f){
  u32 x = __float_as_uint(f);
  u32 r = (x + 0x7fffu + ((x >> 16) & 1u)) >> 16;
  return (u16)r;
}
__device__ __forceinline__ float fsig(float x){ return 1.f / (1.f + __expf(-x)); }
__device__ __forceinline__ float ftanh(float x){
  float e = __expf(2.f * x);
  return 1.f - 2.f / (e + 1.f);
}

__device__ __forceinline__ void gload_lds16(const void* g, void* l){
  __builtin_amdgcn_global_load_lds((const __attribute__((address_space(1))) unsigned int*)g,
                                   (__attribute__((address_space(3))) unsigned int*)l, 16, 0, 0);
}

// ---------------- prep kernels ----------------
__global__ void k_prep_wc(const float* __restrict__ wih, const float* __restrict__ whh,
                          u16* __restrict__ Wc){
  int i = blockIdx.x * 256 + threadIdx.x;       // 0 .. 2097151 (4096*2048/4)
  int r = i >> 9; int k4 = (i & 511) << 2;
  const float* src = (k4 < 1024) ? (wih + (size_t)r * 1024 + k4)
                                 : (whh + (size_t)r * 1024 + (k4 - 1024));
  float4 v = *(const float4*)src;
  u64 pk = (u64)f2bf(v.x) | ((u64)f2bf(v.y) << 16) | ((u64)f2bf(v.z) << 32) | ((u64)f2bf(v.w) << 48);
  *(u64*)(Wc + (size_t)r * 2048 + k4) = pk;
}

__global__ void k_prep_ew(const float* __restrict__ src, u16* __restrict__ dst){
  size_t i = (size_t)(blockIdx.x * 256 + threadIdx.x) * 4;  // up to 32768000
  float4 v = *(const float4*)(src + i);
  u64 pk = (u64)f2bf(v.x) | ((u64)f2bf(v.y) << 16) | ((u64)f2bf(v.z) << 32) | ((u64)f2bf(v.w) << 48);
  *(u64*)(dst + i) = pk;
}

__global__ void k_prep_bsum(const float* __restrict__ bih, const float* __restrict__ bhh,
                            float* __restrict__ bsum){
  int i = blockIdx.x * 256 + threadIdx.x;       // 4096
  bsum[i] = bih[i] + bhh[i];
}

__global__ void k_gather_x(const int* __restrict__ words, const float* __restrict__ embed,
                           u16* __restrict__ X){
  int row = blockIdx.x;                         // 0..8191 = t*32 + b
  int t = row >> 5, b = row & 31;
  int wd = words[b * T_ + t];
  const float* src = embed + (size_t)wd * E_;
  u16* dst = X + (size_t)row * E_;
  int e = threadIdx.x * 4;
  float4 v = *(const float4*)(src + e);
  u64 pk = (u64)f2bf(v.x) | ((u64)f2bf(v.y) << 16) | ((u64)f2bf(v.z) << 32) | ((u64)f2bf(v.w) << 48);
  *(u64*)(dst + e) = pk;
}

// ---------------- sequential LSTM (persistent, 64 blocks x 512 thr) ----------------
// All-register GEMM: weights in VGPRs (4 gates x 8 kk), A-fragments loaded
// directly to registers (x via cache, h via sc0/sc1 L3 loads). Waves 0-3 do
// the x-GEMM k-slices (no dependency -> runs in the sync shadow); waves 4-7
// poll flags then do the h-GEMM k-slices. LDS only holds the 8-way gate
// partials Gp (64 KB). Two barriers per step.
__launch_bounds__(512, 2)
__global__ void k_lstm_seq(const u16* __restrict__ X, const u16* __restrict__ Wc,
                           const float* __restrict__ bsum, u16* __restrict__ Hall,
                           u32* __restrict__ flags){
  __shared__ float Gp[8][4][32][16];   // [wave][gate][m][n] partials, 64 KB

  const int tid  = threadIdx.x;
  const int lane = tid & 63;
  const int w    = tid >> 6;        // 0..7
  const int ph   = w >> 2;          // 0: x-phase waves, 1: h-phase waves
  const int kq   = w & 3;           // 256-wide k-slice within the phase
  const int bid  = blockIdx.x;      // 0..63
  const int nc0  = bid << 4;        // 16 h-columns per block

  // elementwise mapping: one (m,n) cell per thread
  const int em = tid >> 4, en = tid & 15;
  const float bb0 = bsum[nc0 + en];
  const float bb1 = bsum[1024 + nc0 + en];
  const float bb2 = bsum[2048 + nc0 + en];
  const float bb3 = bsum[3072 + nc0 + en];
  float c = 0.f;

  // ---- preload weights: all 4 gates, this wave's 256-k slice (x or h half) ----
  bf16x8 breg[4][8];
  {
    const u16* bp = Wc + (size_t)(nc0 + (lane & 15)) * 2048
                       + (size_t)ph * 1024 + kq * 256 + ((lane >> 4) * 8);
    #pragma unroll
    for (int g = 0; g < 4; ++g)
      #pragma unroll
      for (int kk = 0; kk < 8; ++kk)
        breg[g][kk] = *(const bf16x8*)(bp + (size_t)g * 1024 * 2048 + kk * 32);
  }

  const int arow = lane & 15;          // A row within 16-tile
  const int akg  = (lane >> 4) * 8;    // k sub-group

  for (int t = 0; t < T_; ++t){
    f32x4 acc[4][2];
    #pragma unroll
    for (int g = 0; g < 4; ++g){
      f32x4 z = {0.f,0.f,0.f,0.f};
      acc[g][0] = z; acc[g][1] = z;
    }

    uint4 a0[8], a1[8];
    if (ph == 0){
      // x-waves: plain cached loads of x_t A-fragments (runs in sync shadow)
      const u16* Xt = X + (size_t)t * 32768 + kq * 256 + akg;
      #pragma unroll
      for (int kk = 0; kk < 8; ++kk){
        a0[kk] = *(const uint4*)(Xt + (size_t)arow * 1024 + kk * 32);
        a1[kk] = *(const uint4*)(Xt + (size_t)(16 + arow) * 1024 + kk * 32);
      }
    } else {
      // h-waves: poll per-block flags (lane b watches block b), then L3 loads
      u32 fv;
      do {
        asm volatile("global_load_dword %0, %1, off sc0 sc1\n\ts_waitcnt vmcnt(0)"
                     : "=v"(fv) : "v"(flags + (lane << 5)) : "memory");
      } while (!__all((int)(fv >= (u32)t)));
      const u16* b0 = Hall + (size_t)t * 32768 + (size_t)arow * 1024 + kq * 256 + akg;
      const u16* b1 = b0 + 16 * 1024;
      #pragma unroll
      for (int kk = 0; kk < 8; ++kk){
        asm volatile("global_load_dwordx4 %0, %1, off offset:%2 sc0 sc1"
                     : "=v"(a0[kk]) : "v"(b0), "n"(kk * 64));
        asm volatile("global_load_dwordx4 %0, %1, off offset:%2 sc0 sc1"
                     : "=v"(a1[kk]) : "v"(b1), "n"(kk * 64));
      }
      asm volatile("s_waitcnt vmcnt(0)" ::: "memory");
    }

    // ---- MFMA: each A-fragment pair feeds all 4 gates ----
    #pragma unroll
    for (int kk = 0; kk < 8; ++kk){
      bf16x8 f0 = __builtin_bit_cast(bf16x8, a0[kk]);
      bf16x8 f1 = __builtin_bit_cast(bf16x8, a1[kk]);
      #pragma unroll
      for (int g = 0; g < 4; ++g){
        acc[g][0] = __builtin_amdgcn_mfma_f32_16x16x32_bf16(f0, breg[g][kk], acc[g][0], 0, 0, 0);
        acc[g][1] = __builtin_amdgcn_mfma_f32_16x16x32_bf16(f1, breg[g][kk], acc[g][1], 0, 0, 0);
      }
    }

    // ---- write partials ----
    #pragma unroll
    for (int g = 0; g < 4; ++g)
      #pragma unroll
      for (int mt = 0; mt < 2; ++mt)
        #pragma unroll
        for (int r = 0; r < 4; ++r)
          Gp[w][g][(lane >> 4) * 4 + r + mt * 16][lane & 15] = acc[g][mt][r];
    __syncthreads();

    // ---- elementwise: 512 threads, one (m,n) cell each ----
    {
      float s0 = bb0, s1 = bb1, s2 = bb2, s3 = bb3;
      #pragma unroll
      for (int p = 0; p < 8; ++p){
        s0 += Gp[p][0][em][en];
        s1 += Gp[p][1][em][en];
        s2 += Gp[p][2][em][en];
        s3 += Gp[p][3][em][en];
      }
      float ig = fsig(s0), fg = fsig(s1), gg = ftanh(s2), og = fsig(s3);
      c = fg * c + ig * gg;
      float h = og * ftanh(c);
      u32 hb = (u32)f2bf(h);
      const u16* hp = Hall + (size_t)(t + 1) * 32768 + (size_t)em * 1024 + nc0 + en;
      asm volatile("global_store_short %0, %1, off sc0 sc1" :: "v"(hp), "v"(hb) : "memory");
    }
    asm volatile("s_waitcnt vmcnt(0)" ::: "memory");
    __syncthreads();   // all h stores of this block drained & visible at L3
    if (tid == 0){
      u32 fv = (u32)(t + 1);
      asm volatile("global_store_dword %0, %1, off sc0 sc1"
                   :: "v"(flags + (bid << 5)), "v"(fv) : "memory");
    }
  }
}

// ---------------- batched emit GEMM with fused exp-row-sum ----------------
__launch_bounds__(256)
__global__ void k_emit(const u16* __restrict__ Hall, const u16* __restrict__ Ew,
                       const float* __restrict__ emit_b, float* __restrict__ partials){
  __shared__ u16 As[128 * 32];
  __shared__ u16 Bs[128 * 32];
  __shared__ float rs[2 * 128];
  const int tid = threadIdx.x, lane = tid & 63, w = tid >> 6;
  const int wr = w >> 1, wc = w & 1;
  const int vc = blockIdx.x;   // 0..249
  const int mt = blockIdx.y;   // 0..63
  const u16* Ab = Hall + 32 * 1024 + (size_t)mt * 128 * 1024;
  const u16* Bb = Ew + (size_t)vc * 128 * 1024;

  f32x4 z = {0.f,0.f,0.f,0.f};
  f32x4 acc[4][4];
  #pragma unroll
  for (int mi = 0; mi < 4; ++mi)
    #pragma unroll
    for (int ni = 0; ni < 4; ++ni) acc[mi][ni] = z;

  for (int kk = 0; kk < 32; ++kk){
    #pragma unroll
    for (int p = 0; p < 2; ++p){
      int u = (p << 8) + tid;             // 0..511
      int row = u >> 2, seg = u & 3;
      size_t go = (size_t)row * 1024 + (size_t)kk * 32 + seg * 8;
      gload_lds16(Ab + go, (char*)As + (size_t)u * 16);
      gload_lds16(Bb + go, (char*)Bs + (size_t)u * 16);
    }
    __syncthreads();
    bf16x8 af[4], bf[4];
    #pragma unroll
    for (int mi = 0; mi < 4; ++mi){
      int row = wr * 64 + mi * 16 + (lane & 15);
      af[mi] = *(const bf16x8*)(As + row * 32 + ((lane >> 4) * 8));
    }
    #pragma unroll
    for (int ni = 0; ni < 4; ++ni){
      int row = wc * 64 + ni * 16 + (lane & 15);
      bf[ni] = *(const bf16x8*)(Bs + row * 32 + ((lane >> 4) * 8));
    }
    #pragma unroll
    for (int mi = 0; mi < 4; ++mi)
      #pragma unroll
      for (int ni = 0; ni < 4; ++ni)
        acc[mi][ni] = __builtin_amdgcn_mfma_f32_16x16x32_bf16(af[mi], bf[ni], acc[mi][ni], 0, 0, 0);
    __syncthreads();
  }

  // epilogue: exp + row-sum over this block's 128 v-columns
  float eb[4];
  #pragma unroll
  for (int ni = 0; ni < 4; ++ni)
    eb[ni] = emit_b[vc * 128 + wc * 64 + ni * 16 + (lane & 15)];
  #pragma unroll
  for (int mi = 0; mi < 4; ++mi){
    #pragma unroll
    for (int r = 0; r < 4; ++r){
      float s = 0.f;
      #pragma unroll
      for (int ni = 0; ni < 4; ++ni) s += __expf(acc[mi][ni][r] + eb[ni]);
      s += __shfl_xor(s, 1); s += __shfl_xor(s, 2); s += __shfl_xor(s, 4); s += __shfl_xor(s, 8);
      if ((lane & 15) == 0)
        rs[wc * 128 + wr * 64 + mi * 16 + ((lane >> 4) << 2) + r] = s;
    }
  }
  __syncthreads();
  if (tid < 128){
    partials[(size_t)vc * 8192 + (size_t)mt * 128 + tid] = rs[tid] + rs[128 + tid];
  }
}

// ---------------- target logit per row ----------------
__global__ void k_target(const u16* __restrict__ Hall, const u16* __restrict__ Ew,
                         const int* __restrict__ words, const float* __restrict__ emit_b,
                         float* __restrict__ tgt){
  int row  = blockIdx.x * 4 + (threadIdx.x >> 6);  // 0..8191
  int lane = threadIdx.x & 63;
  int t = row >> 5, b = row & 31;
  int wd = words[b * T_ + t];
  const bf16x8* ha = (const bf16x8*)(Hall + (size_t)(row + 32) * 1024 + lane * 16);
  const bf16x8* wa = (const bf16x8*)(Ew + (size_t)wd * 1024 + lane * 16);
  float s = 0.f;
  #pragma unroll
  for (int p = 0; p < 2; ++p){
    bf16x8 av = ha[p], wv = wa[p];
    #pragma unroll
    for (int i = 0; i < 8; ++i) s += bf2f((u16)av[i]) * bf2f((u16)wv[i]);
  }
  s += __shfl_xor(s, 32); s += __shfl_xor(s, 16); s += __shfl_xor(s, 8);
  s += __shfl_xor(s, 4);  s += __shfl_xor(s, 2);  s += __shfl_xor(s, 1);
  if (lane == 0) tgt[row] = s + emit_b[wd];
}

// ---------------- finalize: ll = tgt - log(sum exp) ----------------
__global__ void k_final(const float* __restrict__ partials, const float* __restrict__ tgt,
                        float* __restrict__ out){
  int i = blockIdx.x * 256 + threadIdx.x;    // 0..8191
  float s = 0.f;
  for (int vcb = 0; vcb < 250; ++vcb) s += partials[(size_t)vcb * 8192 + i];
  out[i] = tgt[i] - logf(s);
}

extern "C" void kernel_launch(void* const* d_in, const int* in_sizes, int n_in,
                              void* d_out, int out_size, void* d_ws, size_t ws_size,
                              hipStream_t stream){
  const int*   words = (const int*)d_in[0];
  const float* embed = (const float*)d_in[1];
  const float* wih   = (const float*)d_in[2];
  const float* whh   = (const float*)d_in[3];
  const float* bih   = (const float*)d_in[4];
  const float* bhh   = (const float*)d_in[5];
  const float* emw   = (const float*)d_in[6];
  const float* emb_b = (const float*)d_in[7];
  float* out = (float*)d_out;

  // workspace layout
  char* ws = (char*)d_ws;
  u16* Wc   = (u16*)ws;                       // 4096*2048
  u16* Ew   = Wc + 8388608ULL;                // 32000*1024
  u16* X    = Ew + 32768000ULL;               // 256*32*1024
  u16* Hall = X + 8388608ULL;                 // 257*32*1024 (slot 0 = h_init zeros)
  float* fb   = (float*)(Hall + 8421376ULL);
  float* bsum = fb;                           // 4096
  float* tgt  = fb + 4096;                    // 8192
  float* parts= fb + 4096 + 8192;             // 250*8192
  u32* flags  = (u32*)(parts + 2048000ULL);   // 64 flags, 128B apart

  size_t need = (8388608ULL + 32768000ULL + 8388608ULL + 8421376ULL) * 2
              + (4096ULL + 8192ULL + 2048000ULL) * 4 + 64ULL * 32 * 4;
  if (ws_size < need) return;  // fail loudly via validation

  hipMemsetAsync(flags, 0, 64 * 32 * 4, stream);
  hipMemsetAsync(Hall, 0, 32 * 1024 * 2, stream);   // h_{-1} = 0

  k_prep_wc  <<<8192,  256, 0, stream>>>(wih, whh, Wc);
  k_prep_ew  <<<32000, 256, 0, stream>>>(emw, Ew);
  k_prep_bsum<<<16,    256, 0, stream>>>(bih, bhh, bsum);
  k_gather_x <<<8192,  256, 0, stream>>>(words, embed, X);
  k_lstm_seq <<<64,    512, 0, stream>>>(X, Wc, bsum, Hall, flags);
  k_emit     <<<dim3(250, 64), 256, 0, stream>>>(Hall, Ew, emb_b, parts);
  k_target   <<<2048,  256, 0, stream>>>(Hall, Ew, words, emb_b, tgt);
  k_final    <<<32,    256, 0, stream>>>(parts, tgt, out);
}

// Round 6
// 1497.489 us; speedup vs baseline: 3.3377x; 1.5538x over previous
//
#include <hip/hip_runtime.h>
#include <stdint.h>

#define B_ 32
#define T_ 256
#define E_ 1024
#define H_ 1024
#define V_ 32000

typedef unsigned short u16;
typedef unsigned int   u32;
typedef unsigned long long u64;

typedef __attribute__((ext_vector_type(8))) short bf16x8;
typedef __attribute__((ext_vector_type(4))) float f32x4;

__device__ __forceinline__ float bf2f(u16 u){ u32 x = ((u32)u) << 16; return __uint_as_float(x); }
__device__ __forceinline__ u16  f2bf(float f){
  u32 x = __float_as_uint(f);
  u32 r = (x + 0x7fffu + ((x >> 16) & 1u)) >> 16;
  return (u16)r;
}
__device__ __forceinline__ float fsig(float x){ return 1.f / (1.f + __expf(-x)); }
__device__ __forceinline__ float ftanh(float x){
  float e = __expf(2.f * x);
  return 1.f - 2.f / (e + 1.f);
}

__device__ __forceinline__ void gload_lds16(const void* g, void* l){
  __builtin_amdgcn_global_load_lds((const __attribute__((address_space(1))) unsigned int*)g,
                                   (__attribute__((address_space(3))) unsigned int*)l, 16, 0, 0);
}

// ---------------- prep kernels ----------------
__global__ void k_prep_wc(const float* __restrict__ wih, const float* __restrict__ whh,
                          u16* __restrict__ Wc){
  int i = blockIdx.x * 256 + threadIdx.x;
  int r = i >> 9; int k4 = (i & 511) << 2;
  const float* src = (k4 < 1024) ? (wih + (size_t)r * 1024 + k4)
                                 : (whh + (size_t)r * 1024 + (k4 - 1024));
  float4 v = *(const float4*)src;
  u64 pk = (u64)f2bf(v.x) | ((u64)f2bf(v.y) << 16) | ((u64)f2bf(v.z) << 32) | ((u64)f2bf(v.w) << 48);
  *(u64*)(Wc + (size_t)r * 2048 + k4) = pk;
}

__global__ void k_prep_ew(const float* __restrict__ src, u16* __restrict__ dst){
  size_t i = (size_t)(blockIdx.x * 256 + threadIdx.x) * 4;
  float4 v = *(const float4*)(src + i);
  u64 pk = (u64)f2bf(v.x) | ((u64)f2bf(v.y) << 16) | ((u64)f2bf(v.z) << 32) | ((u64)f2bf(v.w) << 48);
  *(u64*)(dst + i) = pk;
}

__global__ void k_prep_bsum(const float* __restrict__ bih, const float* __restrict__ bhh,
                            float* __restrict__ bsum){
  int i = blockIdx.x * 256 + threadIdx.x;
  bsum[i] = bih[i] + bhh[i];
}

__global__ void k_gather_x(const int* __restrict__ words, const float* __restrict__ embed,
                           u16* __restrict__ X){
  int row = blockIdx.x;                         // t*32 + b
  int t = row >> 5, b = row & 31;
  int wd = words[b * T_ + t];
  const float* src = embed + (size_t)wd * E_;
  u16* dst = X + (size_t)row * E_;
  int e = threadIdx.x * 4;
  float4 v = *(const float4*)(src + e);
  u64 pk = (u64)f2bf(v.x) | ((u64)f2bf(v.y) << 16) | ((u64)f2bf(v.z) << 32) | ((u64)f2bf(v.w) << 48);
  *(u64*)(dst + e) = pk;
}

// ---------------- shared 256x128 GEMM tile core (swizzled LDS) ----------------
// A: 256 rows, stride 1024 u16. B: 128 rows, stride (1<<blog2) u16. K = 1024.
// LDS: As @ sm[0..16K), Bs @ sm[16K..24K). Swizzle: seg ^= (row>>1)&3, applied
// on the gload SOURCE (inverse) and the ds_read address (both sides, rule #21).
__device__ __forceinline__ void tile_gemm(const u16* __restrict__ Ab, const u16* __restrict__ Bb,
                                          int blog2, char* sm, f32x4 (&acc)[4][4],
                                          int tid, int lane, int wr, int wc){
  char* As = sm;
  char* Bs = sm + 16384;
  for (int kk = 0; kk < 32; ++kk){
    {
      int u0 = tid;
      int r0 = u0 >> 2, s0 = (u0 & 3) ^ ((r0 >> 1) & 3);
      gload_lds16(Ab + (((size_t)r0) << 10) + kk * 32 + s0 * 8, As + (size_t)u0 * 16);
      int u1 = 512 + tid;
      int r1 = u1 >> 2, s1 = (u1 & 3) ^ ((r1 >> 1) & 3);
      gload_lds16(Ab + (((size_t)r1) << 10) + kk * 32 + s1 * 8, As + (size_t)u1 * 16);
      int r2 = tid >> 2, s2 = (tid & 3) ^ ((r2 >> 1) & 3);
      gload_lds16(Bb + (((size_t)r2) << blog2) + kk * 32 + s2 * 8, Bs + (size_t)tid * 16);
    }
    __syncthreads();
    bf16x8 af[4], bfr[4];
    #pragma unroll
    for (int mi = 0; mi < 4; ++mi){
      int r = wr * 64 + mi * 16 + (lane & 15);
      u32 byte = ((u32)r << 6) + (((u32)lane >> 4) << 4);
      byte ^= (u32)(r & 6) << 3;
      af[mi] = *(const bf16x8*)(As + byte);
    }
    #pragma unroll
    for (int ni = 0; ni < 4; ++ni){
      int r = wc * 64 + ni * 16 + (lane & 15);
      u32 byte = ((u32)r << 6) + (((u32)lane >> 4) << 4);
      byte ^= (u32)(r & 6) << 3;
      bfr[ni] = *(const bf16x8*)(Bs + byte);
    }
    #pragma unroll
    for (int mi = 0; mi < 4; ++mi)
      #pragma unroll
      for (int ni = 0; ni < 4; ++ni)
        acc[mi][ni] = __builtin_amdgcn_mfma_f32_16x16x32_bf16(af[mi], bfr[ni], acc[mi][ni], 0, 0, 0);
    __syncthreads();
  }
}

// ---------------- k_xgemm: Xg (COL-MAJOR [4096][8192]) = X @ Wih^T + bsum -----------
// Separate kernel (kernel boundary = global sync) -> no runtime gating needed.
__launch_bounds__(512, 2)
__global__ void k_xgemm(const u16* __restrict__ X, const u16* __restrict__ Wc,
                        const float* __restrict__ bsum, u16* __restrict__ Xg){
  __shared__ __align__(16) char smem[24576];
  const int tid = threadIdx.x, lane = tid & 63, w = tid >> 6;
  const int wr = w >> 1, wc = w & 1;
  const int mtx = blockIdx.x >> 5, vcx = blockIdx.x & 31;
  const u16* Ab = X + (size_t)mtx * 256 * 1024;
  const u16* Bb = Wc + (size_t)vcx * 128 * 2048;
  f32x4 acc[4][4];
  #pragma unroll
  for (int mi = 0; mi < 4; ++mi)
    #pragma unroll
    for (int ni = 0; ni < 4; ++ni){ f32x4 z = {0.f,0.f,0.f,0.f}; acc[mi][ni] = z; }
  tile_gemm(Ab, Bb, 11, smem, acc, tid, lane, wr, wc);
  float bcol[4];
  #pragma unroll
  for (int ni = 0; ni < 4; ++ni)
    bcol[ni] = bsum[vcx * 128 + wc * 64 + ni * 16 + (lane & 15)];
  int colb = vcx * 128 + wc * 64 + (lane & 15);
  int rowb = mtx * 256 + wr * 64 + ((lane >> 4) << 2);
  #pragma unroll
  for (int mi = 0; mi < 4; ++mi){
    #pragma unroll
    for (int ni = 0; ni < 4; ++ni){
      float b = bcol[ni];
      u32 lo = (u32)f2bf(acc[mi][ni][0] + b) | ((u32)f2bf(acc[mi][ni][1] + b) << 16);
      u32 hi = (u32)f2bf(acc[mi][ni][2] + b) | ((u32)f2bf(acc[mi][ni][3] + b) << 16);
      uint2 pk; pk.x = lo; pk.y = hi;
      *(uint2*)(Xg + (size_t)(colb + ni * 16) * 8192 + rowb + mi * 16) = pk;
    }
  }
}

// ---------------- emit tile: exp-row-sum of Hall[mt] @ Ew[vc]^T + emit_b ----------------
__device__ __forceinline__ void emit_tile(int qi, const u16* __restrict__ Hall,
                                          const u16* __restrict__ Ew,
                                          const float* __restrict__ emit_b,
                                          float* __restrict__ parts,
                                          u32* __restrict__ flags,
                                          char* sm, int tid, int lane, int w){
  u32 mt = (u32)qi / 250u, vc = (u32)qi % 250u;
  int wr = w >> 1, wc = w & 1;
  // gate: all 64 producer flags >= mt*8+8 (wave 0 polls, block barrier after).
  // Bounded budget: on expiry proceed (wrong data but no hang -> diagnosable).
  if (w == 0){
    u32 tgtv = mt * 8u + 8u;
    u32 budget = 1u << 20;
    const u32* fp = flags + (lane << 5);
    for (;;){
      u32 fv;
      asm volatile("global_load_dword %0, %1, off sc0 sc1\n\ts_waitcnt vmcnt(0)"
                   : "=v"(fv) : "v"(fp) : "memory");
      if (__all((int)(fv >= tgtv)) || !--budget) break;
      __builtin_amdgcn_s_sleep(16);
    }
  }
  __syncthreads();
  const u16* Ab = Hall + 32 * 1024 + (size_t)mt * 256 * 1024;
  const u16* Bb = Ew + (size_t)vc * 128 * 1024;
  f32x4 acc[4][4];
  #pragma unroll
  for (int mi = 0; mi < 4; ++mi)
    #pragma unroll
    for (int ni = 0; ni < 4; ++ni){ f32x4 z = {0.f,0.f,0.f,0.f}; acc[mi][ni] = z; }
  tile_gemm(Ab, Bb, 10, sm, acc, tid, lane, wr, wc);
  float* rs = (float*)(sm + 24576);   // [2][256]
  float eb[4];
  #pragma unroll
  for (int ni = 0; ni < 4; ++ni)
    eb[ni] = emit_b[vc * 128 + wc * 64 + ni * 16 + (lane & 15)];
  #pragma unroll
  for (int mi = 0; mi < 4; ++mi){
    #pragma unroll
    for (int r = 0; r < 4; ++r){
      float s = 0.f;
      #pragma unroll
      for (int ni = 0; ni < 4; ++ni) s += __expf(acc[mi][ni][r] + eb[ni]);
      s += __shfl_xor(s, 1); s += __shfl_xor(s, 2); s += __shfl_xor(s, 4); s += __shfl_xor(s, 8);
      if ((lane & 15) == 0)
        rs[wc * 256 + wr * 64 + mi * 16 + ((lane >> 4) << 2) + r] = s;
    }
  }
  __syncthreads();
  if (tid < 256)
    parts[(size_t)vc * 8192 + (size_t)mt * 256 + tid] = rs[tid] + rs[256 + tid];
  __syncthreads();
}

// ---------------- mega kernel: LSTM recurrence (blocks 0-63) + emit workers -----------
// Dependency graph is ACYCLIC: LSTM -> flags -> emit. No worker output feeds the LSTM.
__launch_bounds__(512, 2)
__global__ void k_mega(const u16* __restrict__ Wc, const u16* __restrict__ Xg,
                       const u16* __restrict__ Ew, const float* __restrict__ emit_b,
                       u16* __restrict__ Hall, float* __restrict__ parts,
                       u32* __restrict__ ctrl){
  __shared__ __align__(16) char smem[65536];
  __shared__ int qshare;
  u32* q2    = ctrl;              // emit tile queue
  u32* flags = ctrl + 1024;       // [64] stride-32 u32 (128B apart)

  const int tid  = threadIdx.x;
  const int lane = tid & 63;
  const int w    = tid >> 6;
  const int bid  = blockIdx.x;

  if (bid >= 64){
    // -------- worker role: drain emit queue --------
    for (;;){
      if (tid == 0) qshare = (int)__hip_atomic_fetch_add(q2, 1u, __ATOMIC_RELAXED, __HIP_MEMORY_SCOPE_AGENT);
      __syncthreads();
      int qi = qshare;
      __syncthreads();
      if (qi >= 8000) break;
      emit_tile(qi, Hall, Ew, emit_b, parts, flags, smem, tid, lane, w);
    }
    return;
  }

  // -------- lstm role (blocks 0..63) --------
  const int nc0  = bid << 4;
  const int em   = tid >> 4, en = tid & 15;
  const int arow = lane & 15;
  const int akg  = (lane >> 4) << 3;
  float c = 0.f;
  float* Gp = (float*)smem;   // [8][4][32][16]

  // weights: all 4 gates, K-slice w*128 (h-half of Wc = offset 1024)
  bf16x8 breg[4][4];
  {
    const u16* bp = Wc + (((size_t)(nc0 + arow)) << 11) + 1024 + (w << 7) + akg;
    #pragma unroll
    for (int g = 0; g < 4; ++g)
      #pragma unroll
      for (int kk = 0; kk < 4; ++kk)
        breg[g][kk] = *(const bf16x8*)(bp + (((size_t)g) << 21) + (kk << 5));
  }

  // col-major Xg base for this thread's cell (gate g at +g*1024*8192)
  const u16* xgb = Xg + (size_t)(nc0 + en) * 8192 + em;

  for (int t = 0; t < T_; ++t){
    // 1. flag poll: wave w consumes h cols [w*128, w*128+128) = blocks 8w..8w+7
    {
      const u32* fp = flags + ((8 * w + (lane & 7)) << 5);
      u32 budget = 1u << 22;
      u32 fv;
      do {
        asm volatile("global_load_dword %0, %1, off sc0 sc1\n\ts_waitcnt vmcnt(0)"
                     : "=v"(fv) : "v"(fp) : "memory");
      } while (!__all((int)(fv >= (u32)t)) && --budget);
    }
    // 2. h fragment loads (sc, L3)
    uint4 a0[4], a1[4];
    {
      const u16* h0 = Hall + (((size_t)t) << 15) + (((size_t)arow) << 10) + (w << 7) + akg;
      const u16* h1 = h0 + 16384;
      #pragma unroll
      for (int kk = 0; kk < 4; ++kk){
        asm volatile("global_load_dwordx4 %0, %1, off offset:%2 sc0 sc1"
                     : "=v"(a0[kk]) : "v"(h0), "n"(kk * 64));
        asm volatile("global_load_dwordx4 %0, %1, off offset:%2 sc0 sc1"
                     : "=v"(a1[kk]) : "v"(h1), "n"(kk * 64));
      }
    }
    // 3. Xg loads (plain cached; produced by k_xgemm before this kernel)
    u16 x0 = xgb[(size_t)t * 32];
    u16 x1 = xgb[1024ull * 8192 + (size_t)t * 32];
    u16 x2 = xgb[2048ull * 8192 + (size_t)t * 32];
    u16 x3 = xgb[3072ull * 8192 + (size_t)t * 32];
    asm volatile("s_waitcnt vmcnt(0)" ::: "memory");
    __builtin_amdgcn_sched_barrier(0);   // rule #18: keep MFMAs below the wait

    // 4. MFMA: 4 gates x 2 M-tiles x 4 k-steps
    f32x4 acc[4][2];
    #pragma unroll
    for (int g = 0; g < 4; ++g){ f32x4 z = {0.f,0.f,0.f,0.f}; acc[g][0] = z; acc[g][1] = z; }
    #pragma unroll
    for (int kk = 0; kk < 4; ++kk){
      bf16x8 f0 = __builtin_bit_cast(bf16x8, a0[kk]);
      bf16x8 f1 = __builtin_bit_cast(bf16x8, a1[kk]);
      #pragma unroll
      for (int g = 0; g < 4; ++g){
        acc[g][0] = __builtin_amdgcn_mfma_f32_16x16x32_bf16(f0, breg[g][kk], acc[g][0], 0, 0, 0);
        acc[g][1] = __builtin_amdgcn_mfma_f32_16x16x32_bf16(f1, breg[g][kk], acc[g][1], 0, 0, 0);
      }
    }
    // 5. partials to LDS
    #pragma unroll
    for (int g = 0; g < 4; ++g)
      #pragma unroll
      for (int mt2 = 0; mt2 < 2; ++mt2)
        #pragma unroll
        for (int r = 0; r < 4; ++r){
          int m = ((lane >> 4) << 2) + r + mt2 * 16;
          Gp[((w * 4 + g) * 32 + m) * 16 + (lane & 15)] = acc[g][mt2][r];
        }
    __syncthreads();

    // 6. elementwise (thread = one (em,en) cell), publish h_{t+1}
    {
      float s0 = bf2f(x0), s1 = bf2f(x1), s2 = bf2f(x2), s3 = bf2f(x3);
      #pragma unroll
      for (int p = 0; p < 8; ++p){
        s0 += Gp[((p * 4 + 0) * 32 + em) * 16 + en];
        s1 += Gp[((p * 4 + 1) * 32 + em) * 16 + en];
        s2 += Gp[((p * 4 + 2) * 32 + em) * 16 + en];
        s3 += Gp[((p * 4 + 3) * 32 + em) * 16 + en];
      }
      float ig = fsig(s0), fg = fsig(s1), gg = ftanh(s2), og = fsig(s3);
      c = fg * c + ig * gg;
      float h = og * ftanh(c);
      u32 hb = (u32)f2bf(h);
      const u16* hp = Hall + (((size_t)(t + 1)) << 15) + (((size_t)em) << 10) + nc0 + en;
      asm volatile("global_store_short %0, %1, off sc0 sc1" :: "v"(hp), "v"(hb) : "memory");
    }
    asm volatile("s_waitcnt vmcnt(0)" ::: "memory");
    __syncthreads();
    if (tid == 0){
      u32 fv = (u32)(t + 1);
      asm volatile("global_store_dword %0, %1, off sc0 sc1"
                   :: "v"(flags + (bid << 5)), "v"(fv) : "memory");
    }
  }

  // done with recurrence: help drain emit queue
  for (;;){
    if (tid == 0) qshare = (int)__hip_atomic_fetch_add(q2, 1u, __ATOMIC_RELAXED, __HIP_MEMORY_SCOPE_AGENT);
    __syncthreads();
    int qi = qshare;
    __syncthreads();
    if (qi >= 8000) break;
    emit_tile(qi, Hall, Ew, emit_b, parts, flags, smem, tid, lane, w);
  }
}

// ---------------- target logit per row ----------------
__global__ void k_target(const u16* __restrict__ Hall, const u16* __restrict__ Ew,
                         const int* __restrict__ words, const float* __restrict__ emit_b,
                         float* __restrict__ tgt){
  int row  = blockIdx.x * 4 + (threadIdx.x >> 6);
  int lane = threadIdx.x & 63;
  int t = row >> 5, b = row & 31;
  int wd = words[b * T_ + t];
  const bf16x8* ha = (const bf16x8*)(Hall + (size_t)(row + 32) * 1024 + lane * 16);
  const bf16x8* wa = (const bf16x8*)(Ew + (size_t)wd * 1024 + lane * 16);
  float s = 0.f;
  #pragma unroll
  for (int p = 0; p < 2; ++p){
    bf16x8 av = ha[p], wv = wa[p];
    #pragma unroll
    for (int i = 0; i < 8; ++i) s += bf2f((u16)av[i]) * bf2f((u16)wv[i]);
  }
  s += __shfl_xor(s, 32); s += __shfl_xor(s, 16); s += __shfl_xor(s, 8);
  s += __shfl_xor(s, 4);  s += __shfl_xor(s, 2);  s += __shfl_xor(s, 1);
  if (lane == 0) tgt[row] = s + emit_b[wd];
}

// ---------------- finalize ----------------
__global__ void k_final(const float* __restrict__ partials, const float* __restrict__ tgt,
                        float* __restrict__ out){
  int i = blockIdx.x * 256 + threadIdx.x;
  float s = 0.f;
  for (int vcb = 0; vcb < 250; ++vcb) s += partials[(size_t)vcb * 8192 + i];
  out[i] = tgt[i] - logf(s);
}

extern "C" void kernel_launch(void* const* d_in, const int* in_sizes, int n_in,
                              void* d_out, int out_size, void* d_ws, size_t ws_size,
                              hipStream_t stream){
  const int*   words = (const int*)d_in[0];
  const float* embed = (const float*)d_in[1];
  const float* wih   = (const float*)d_in[2];
  const float* whh   = (const float*)d_in[3];
  const float* bih   = (const float*)d_in[4];
  const float* bhh   = (const float*)d_in[5];
  const float* emw   = (const float*)d_in[6];
  const float* emb_b = (const float*)d_in[7];
  float* out = (float*)d_out;

  // workspace layout (bytes)
  char* ws = (char*)d_ws;
  u16* Wc   = (u16*)ws;                          // 16,777,216 B
  u16* Ew   = (u16*)(ws + 16777216);             // 65,536,000 B
  u16* X    = (u16*)(ws + 82313216);             // 16,777,216 B
  u16* Hall = (u16*)(ws + 99090432);             // 16,842,752 B (257*32*1024 u16)
  u16* Xg   = (u16*)(ws + 115933184);            // 67,108,864 B (col-major [4096][8192] u16)
  float* bsum = (float*)(ws + 183042048);        // 16,384 B
  float* tgt  = (float*)(ws + 183058432);        // 32,768 B
  float* parts= (float*)(ws + 183091200);        // 8,192,000 B
  u32*  ctrl  = (u32*)(ws + 191283200);          // 16,384 B
  size_t need = 191283200ULL + 16384ULL;
  if (ws_size < need) return;  // fail loudly via validation

  hipMemsetAsync(ctrl, 0, 16384, stream);
  hipMemsetAsync(Hall, 0, 32 * 1024 * 2, stream);   // h_{-1} = 0

  k_prep_wc  <<<8192,  256, 0, stream>>>(wih, whh, Wc);
  k_prep_ew  <<<32000, 256, 0, stream>>>(emw, Ew);
  k_prep_bsum<<<16,    256, 0, stream>>>(bih, bhh, bsum);
  k_gather_x <<<8192,  256, 0, stream>>>(words, embed, X);
  k_xgemm    <<<1024,  512, 0, stream>>>(X, Wc, bsum, Xg);
  k_mega     <<<256,   512, 0, stream>>>(Wc, Xg, Ew, emb_b, Hall, parts, ctrl);
  k_target   <<<2048,  256, 0, stream>>>(Hall, Ew, words, emb_b, tgt);
  k_final    <<<32,    256, 0, stream>>>(parts, tgt, out);
}